// Round 11
// baseline (124.214 us; speedup 1.0000x reference)
//
#include <hip/hip_runtime.h>

// Problem constants (match reference)
#define B 512
#define D 512
#define NC 100000
#define BETA 0.1f
#define MARGIN 50.0f
#define TPB 256
#define NFLOAT (NC * D)            // 51,200,000 floats in new_centers
// Aligned f4 groups of the OUT buffer: group g = out[4g..4g+4).
// Group 0 holds loss + centers[0..2] (patched scalar); groups [1, NG) are bulk.
// out[4g+0]=centers[4g-1]=src4[g-1].w ; out[4g+1..3]=src4[g].x/.y/.z
#define NG 12800000
#define KAE 4350001                // kA copies [1, KAE)
#define KBE 8700001                // kB copies [KAE, KBE); kC copies [KBE, NG)

typedef float f4 __attribute__((ext_vector_type(4)));

// Block-chunked contiguous copy: block bi of nblk owns one contiguous span of
// groups. Per main iteration the block covers 8*TPB*16B = 32KB contiguous ->
// good DRAM row locality. All loop bounds are block-uniform, so every lane
// executes every __shfl_up in lockstep (loads clamped, stores predicated).
__device__ __forceinline__ void copy_span(const f4* __restrict__ src4, f4* __restrict__ dst4,
                                          int lo, int hi, int bi, int nblk, int tid)
{
    const int total = hi - lo;
    const int per = (total + nblk - 1) / nblk;
    const int s = lo + bi * per;
    int e = s + per; if (e > hi) e = hi;
    if (s >= hi) return;
    const int lane = tid & 63;
    int base = s;
    for (; base + 8 * TPB <= e; base += 8 * TPB) {
        const int g = base + tid;
        f4 v[8];
        #pragma unroll
        for (int u = 0; u < 8; ++u) v[u] = src4[g + u * TPB];
        float pw[8];
        #pragma unroll
        for (int u = 0; u < 8; ++u) {
            pw[u] = __shfl_up(v[u].w, 1, 64);
            if (lane == 0) pw[u] = src4[g + u * TPB - 1].w;
        }
        #pragma unroll
        for (int u = 0; u < 8; ++u) {
            f4 o = { pw[u], v[u].x, v[u].y, v[u].z };
            __builtin_nontemporal_store(o, dst4 + (g + u * TPB));
        }
    }
    for (; base < e; base += TPB) {
        const int g = base + tid;
        const int gc = (g < hi) ? g : (hi - 1);
        f4 v = src4[gc];
        float pw = __shfl_up(v.w, 1, 64);
        if (lane == 0) pw = src4[gc - 1].w;
        if (g < e) {
            f4 o = { pw, v.x, v.y, v.z };
            __builtin_nontemporal_store(o, dst4 + g);
        }
    }
}

// ---- kA: blocks 0-511 gather cg + loss partial + winner (+zero maskCnt); 512-2047 copy ----
__global__ __launch_bounds__(TPB) void kA_gather(
    const float* __restrict__ centers, const float* __restrict__ features,
    const int* __restrict__ labels, float* __restrict__ cgbuf,
    float* __restrict__ rowLoss, int* __restrict__ winner, int* __restrict__ maskCnt,
    float* __restrict__ outAll)
{
    const int b = blockIdx.x, t = threadIdx.x;
    if (b < B) {
        __shared__ float red[TPB];
        __shared__ int labs[B];
        __shared__ int wsh;
        if (b == 0 && t == 0) *maskCnt = 0;
        labs[t] = labels[t]; labs[t + 256] = labels[t + 256];
        if (t == 0) wsh = 1;
        __syncthreads();
        const int i = b;
        const int li = labs[i];
        const float2* crow = (const float2*)(centers + (size_t)li * D);
        const float2* frow = (const float2*)(features + (size_t)i * D);
        float2 c = crow[t], f = frow[t];
        ((float2*)(cgbuf + (size_t)i * D))[t] = c;
        float dx = c.x - f.x, dy = c.y - f.y;
        red[t] = fminf(fmaxf(dx * dx, 1e-12f), 1e12f) + fminf(fmaxf(dy * dy, 1e-12f), 1e12f);
        for (int j = i + 1 + t; j < B; j += TPB)
            if (labs[j] == li) wsh = 0;           // benign race, same value
        __syncthreads();
        for (int s = 128; s; s >>= 1) { if (t < s) red[t] += red[t + s]; __syncthreads(); }
        if (t == 0) { rowLoss[i] = red[0]; winner[i] = wsh; }
    } else {
        copy_span((const f4*)centers, (f4*)outAll, 1, KAE, b - 512, 1536, t);
    }
}

// ---- kB: blocks 0-255 pairwise dist tiles + mask count; 256-2047 copy ----
__global__ __launch_bounds__(TPB) void kB_pairdist(
    const float* __restrict__ centers, const int* __restrict__ labels,
    const float* __restrict__ cgbuf, float* __restrict__ dist,
    int* __restrict__ maskCnt, float* __restrict__ outAll)
{
    const int b = blockIdx.x, t = threadIdx.x;
    if (b < 256) {
        __shared__ float As[16][33];
        __shared__ float Bs[16][33];
        __shared__ int redI[TPB];
        const int bi = b >> 4, bj = b & 15;
        const int tx = t & 15, ty = t >> 4;
        float a00 = 0.f, a01 = 0.f, a10 = 0.f, a11 = 0.f;
        for (int k0 = 0; k0 < D; k0 += 16) {
            #pragma unroll
            for (int it = 0; it < 2; ++it) {
                int idx = t + it * 256;              // 0..511
                int r = idx >> 4, kk = idx & 15;
                As[kk][r] = cgbuf[(size_t)(bi * 32 + r) * D + k0 + kk];
                Bs[kk][r] = cgbuf[(size_t)(bj * 32 + r) * D + k0 + kk];
            }
            __syncthreads();
            #pragma unroll
            for (int kk = 0; kk < 16; ++kk) {
                float x0 = As[kk][ty * 2], x1 = As[kk][ty * 2 + 1];
                float y0 = Bs[kk][tx * 2], y1 = Bs[kk][tx * 2 + 1];
                float d00 = x0 - y0, d01 = x0 - y1, d10 = x1 - y0, d11 = x1 - y1;
                a00 += d00 * d00; a01 += d01 * d01; a10 += d10 * d10; a11 += d11 * d11;
            }
            __syncthreads();
        }
        const int r0 = bi * 32 + ty * 2, c0 = bj * 32 + tx * 2;
        float s00 = sqrtf(a00), s01 = sqrtf(a01), s10 = sqrtf(a10), s11 = sqrtf(a11);
        dist[r0 * B + c0]           = s00;
        dist[r0 * B + c0 + 1]       = s01;
        dist[(r0 + 1) * B + c0]     = s10;
        dist[(r0 + 1) * B + c0 + 1] = s11;
        // tile contribution to global sum(mask)
        const int lr0 = labels[r0], lr1 = labels[r0 + 1];
        const int lc0 = labels[c0], lc1 = labels[c0 + 1];
        int cnt = 0;
        cnt += (lr0 != lc0) && (s00 <= MARGIN);
        cnt += (lr0 != lc1) && (s01 <= MARGIN);
        cnt += (lr1 != lc0) && (s10 <= MARGIN);
        cnt += (lr1 != lc1) && (s11 <= MARGIN);
        redI[t] = cnt; __syncthreads();
        for (int s = 128; s; s >>= 1) { if (t < s) redI[t] += redI[t + s]; __syncthreads(); }
        if (t == 0 && redI[0] > 0) atomicAdd(maskCnt, redI[0]);
    } else {
        copy_span((const f4*)centers, (f4*)outAll, KAE, KBE, b - 256, 1792, t);
    }
}

// ---- kC: blocks 0-255 softmax-stats + W-on-the-fly GEMM -> vals; 256 loss+patch; 257+ copy ----
__global__ __launch_bounds__(TPB) void kC_gemm(
    const float* __restrict__ features, const int* __restrict__ labels,
    const float* __restrict__ centers, const float* __restrict__ cgbuf,
    const float* __restrict__ dist, const int* __restrict__ maskCnt,
    const float* __restrict__ rowLoss, float* __restrict__ vals,
    float* __restrict__ out, float* __restrict__ outAll)
{
    const int b = blockIdx.x, t = threadIdx.x;
    float* outC = out + 1;
    if (b < 256) {
        __shared__ float As[16][33];
        __shared__ float Bs[16][33];
        __shared__ int labs[B];
        __shared__ float mxs[32], invZs[32], rowSsh[32];
        labs[t] = labels[t]; labs[t + 256] = labels[t + 256];
        __syncthreads();
        const int bi = b >> 4, bj = b & 15;
        // per-row softmax stats: 8 lanes per row (rows bi*32 .. bi*32+31)
        {
            const int rg = t >> 3, lg = t & 7;
            const int row = bi * 32 + rg;
            const int lr = labs[row];
            const float* drow = dist + row * B;
            float mx = 0.f;
            for (int k = 0; k < 64; ++k) {
                int j = lg + 8 * k;
                float d = drow[j];
                bool m = (labs[j] != lr) && (d <= MARGIN);
                mx = fmaxf(mx, m ? d : 0.f);
            }
            #pragma unroll
            for (int o = 1; o < 8; o <<= 1) mx = fmaxf(mx, __shfl_xor(mx, o, 64));
            float sum = 0.f;
            for (int k = 0; k < 64; ++k) {
                int j = lg + 8 * k;
                float d = drow[j];
                bool m = (labs[j] != lr) && (d <= MARGIN);
                sum += m ? expf(mx - d) : 0.f;
            }
            #pragma unroll
            for (int o = 1; o < 8; o <<= 1) sum += __shfl_xor(sum, o, 64);
            if (lg == 0) {
                float Z = sum + 1e-6f;
                mxs[rg] = mx; invZs[rg] = 1.f / Z; rowSsh[rg] = sum / Z;
            }
        }
        __syncthreads();
        const float flagv = (*maskCnt > 0) ? 1.f : 0.f;
        const int tx = t & 15, ty = t >> 4;
        float a00 = 0.f, a01 = 0.f, a10 = 0.f, a11 = 0.f;
        for (int j0 = 0; j0 < B; j0 += 16) {
            #pragma unroll
            for (int it = 0; it < 2; ++it) {
                int idx = t + it * 256;
                int r = idx >> 4, jj = idx & 15;
                int j = j0 + jj;
                float d = dist[(size_t)(bi * 32 + r) * B + j];
                bool m = (labs[j] != labs[bi * 32 + r]) && (d <= MARGIN);
                As[jj][r] = m ? expf(mxs[r] - d) * invZs[r] : 0.f;
                int c = idx & 31, jj2 = idx >> 5;
                Bs[jj2][c] = cgbuf[(size_t)(j0 + jj2) * D + bj * 32 + c];
            }
            __syncthreads();
            #pragma unroll
            for (int kk = 0; kk < 16; ++kk) {
                float w0 = As[kk][ty * 2], w1 = As[kk][ty * 2 + 1];
                float c0 = Bs[kk][tx * 2], c1 = Bs[kk][tx * 2 + 1];
                a00 += w0 * c0; a01 += w0 * c1; a10 += w1 * c0; a11 += w1 * c1;
            }
            __syncthreads();
        }
        const int i0 = bi * 32 + ty * 2, i1 = i0 + 1;
        const int dcol = bj * 32 + tx * 2;
        const float s0 = rowSsh[ty * 2], s1 = rowSsh[ty * 2 + 1];
        float c, f;
        c = cgbuf[(size_t)i0 * D + dcol];     f = features[(size_t)i0 * D + dcol];
        vals[(size_t)i0 * D + dcol]     = 0.5f * (c + f) - BETA * flagv * (s0 * c - a00);
        c = cgbuf[(size_t)i0 * D + dcol + 1]; f = features[(size_t)i0 * D + dcol + 1];
        vals[(size_t)i0 * D + dcol + 1] = 0.5f * (c + f) - BETA * flagv * (s0 * c - a01);
        c = cgbuf[(size_t)i1 * D + dcol];     f = features[(size_t)i1 * D + dcol];
        vals[(size_t)i1 * D + dcol]     = 0.5f * (c + f) - BETA * flagv * (s1 * c - a10);
        c = cgbuf[(size_t)i1 * D + dcol + 1]; f = features[(size_t)i1 * D + dcol + 1];
        vals[(size_t)i1 * D + dcol + 1] = 0.5f * (c + f) - BETA * flagv * (s1 * c - a11);
    } else if (b == 256) {
        __shared__ float red[TPB];
        red[t] = rowLoss[t] + rowLoss[t + 256]; __syncthreads();
        for (int s = 128; s; s >>= 1) { if (t < s) red[t] += red[t + s]; __syncthreads(); }
        if (t == 0) out[0] = red[0] * (1.0f / ((float)B * (float)D));
        // head (centers[0..2]) and tail (centers[NFLOAT-1]) not covered by the group grid.
        // kD's scatter (next kernel) overwrites these if they belong to winner rows.
        if (t == 1) { outC[0] = centers[0]; outC[1] = centers[1]; outC[2] = centers[2]; }
        if (t == 2) { outC[NFLOAT - 1] = centers[NFLOAT - 1]; }
    } else {
        copy_span((const f4*)centers, (f4*)outAll, KBE, NG, b - 257, 1791, t);
    }
}

// ---- kD: scatter winner rows from vals (runs after ALL copying complete) ----
__global__ __launch_bounds__(TPB) void kD_scatter(
    const float* __restrict__ vals, const int* __restrict__ labels,
    const int* __restrict__ winner, float* __restrict__ outC)
{
    const int b = blockIdx.x, t = threadIdx.x;
    const int i = b * 2 + (t >> 7);          // row 0..511
    const int dcol = (t & 127) * 4;
    if (!winner[i]) return;
    f4 v;
    __builtin_memcpy(&v, &vals[(size_t)i * D + dcol], 16);
    float* dst = outC + (size_t)labels[i] * D + dcol;   // 4B-aligned only
    __builtin_memcpy(dst, &v, 16);
}

extern "C" void kernel_launch(void* const* d_in, const int* in_sizes, int n_in,
                              void* d_out, int out_size, void* d_ws, size_t ws_size,
                              hipStream_t stream)
{
    const float* features = (const float*)d_in[0];
    const int*   labels   = (const int*)d_in[1];
    const float* centers  = (const float*)d_in[2];

    float* out  = (float*)d_out;     // out[0] = loss, out[1..] = new_centers
    float* outC = out + 1;

    char* ws = (char*)d_ws;
    float* cgbuf   = (float*)(ws);                 // 1 MB
    float* dist    = (float*)(ws + 1048576);       // 1 MB
    float* vals    = (float*)(ws + 2097152);       // 1 MB
    float* rowLoss = (float*)(ws + 3145728);       // 2 KB
    int*   winner  = (int*)  (ws + 3147776);       // 2 KB
    int*   maskCnt = (int*)  (ws + 3149824);       // 4 B

    kA_gather<<<2048, TPB, 0, stream>>>(centers, features, labels, cgbuf, rowLoss,
                                        winner, maskCnt, out);
    kB_pairdist<<<2048, TPB, 0, stream>>>(centers, labels, cgbuf, dist, maskCnt, out);
    kC_gemm<<<2048, TPB, 0, stream>>>(features, labels, centers, cgbuf, dist, maskCnt,
                                      rowLoss, vals, out, out);
    kD_scatter<<<256, TPB, 0, stream>>>(vals, labels, winner, outC);
}

// Round 12
// 118.008 us; speedup vs baseline: 1.0526x; 1.0526x over previous
//
#include <hip/hip_runtime.h>

// Problem constants (match reference)
#define B 512
#define D 512
#define NC 100000
#define BETA 0.1f
#define MARGIN 50.0f
#define TPB 256
#define NFLOAT (NC * D)            // 51,200,000 floats in new_centers
// Aligned f4 groups of the OUT buffer: group g = out[4g..4g+4).
// Group 0 holds loss + centers[0..2] (patched scalar); groups [1, NG) are bulk.
// out[4g+0]=centers[4g-1]=src4[g-1].w ; out[4g+1..3]=src4[g].x/.y/.z
#define NG 12800000
#define CSPLIT 5335268             // K1 copies [1, CSPLIT) with 1280 workers; K2 the rest with 1791

typedef float f4 __attribute__((ext_vector_type(4)));

// R10-verbatim grid-strided copy: BOTH sides 16B-aligned; wave-uniform loop bounds
// so every lane executes every __shfl_up in lockstep (loads clamped, stores predicated).
__device__ __forceinline__ void copy_groups(const f4* __restrict__ src4, f4* __restrict__ dst4,
                                            int lo, int hi, int widx, int wstride)
{
    const int lane = widx & 63;
    int g = lo + widx;
    for (; (g - lane) + 63 + 7 * wstride < hi; g += 8 * wstride) {
        f4 v[8];
        #pragma unroll
        for (int u = 0; u < 8; ++u) v[u] = src4[g + u * wstride];
        float pw[8];
        #pragma unroll
        for (int u = 0; u < 8; ++u) {
            pw[u] = __shfl_up(v[u].w, 1, 64);
            if (lane == 0) pw[u] = src4[g + u * wstride - 1].w;
        }
        #pragma unroll
        for (int u = 0; u < 8; ++u) {
            f4 o = { pw[u], v[u].x, v[u].y, v[u].z };
            __builtin_nontemporal_store(o, dst4 + (g + u * wstride));
        }
    }
    for (; (g - lane) < hi; g += wstride) {
        int gc = (g < hi) ? g : (hi - 1);
        f4 v = src4[gc];
        float pw = __shfl_up(v.w, 1, 64);
        if (lane == 0) pw = src4[gc - 1].w;
        if (g < hi) {
            f4 o = { pw, v.x, v.y, v.z };
            __builtin_nontemporal_store(o, dst4 + g);
        }
    }
}

// ---- K1: 0-255 pairdist (inline gather) + maskCnt; 256-767 gather/loss/winner; 768+ copy ----
__global__ __launch_bounds__(TPB) void k1_dist(
    const float* __restrict__ centers, const float* __restrict__ features,
    const int* __restrict__ labels, float* __restrict__ cgbuf, float* __restrict__ dist,
    float* __restrict__ rowLoss, int* __restrict__ winner, int* __restrict__ maskCnt,
    float* __restrict__ outAll)
{
    const int b = blockIdx.x, t = threadIdx.x;
    if (b < 256) {
        __shared__ float As[16][33];
        __shared__ float Bs[16][33];
        __shared__ int labs[B];
        __shared__ int redI[TPB];
        labs[t] = labels[t]; labs[t + 256] = labels[t + 256];
        __syncthreads();
        const int bi = b >> 4, bj = b & 15;
        const int tx = t & 15, ty = t >> 4;
        float a00 = 0.f, a01 = 0.f, a10 = 0.f, a11 = 0.f;
        for (int k0 = 0; k0 < D; k0 += 16) {
            #pragma unroll
            for (int it = 0; it < 2; ++it) {
                int idx = t + it * 256;              // 0..511
                int r = idx >> 4, kk = idx & 15;
                As[kk][r] = centers[(size_t)labs[bi * 32 + r] * D + k0 + kk];
                Bs[kk][r] = centers[(size_t)labs[bj * 32 + r] * D + k0 + kk];
            }
            __syncthreads();
            #pragma unroll
            for (int kk = 0; kk < 16; ++kk) {
                float x0 = As[kk][ty * 2], x1 = As[kk][ty * 2 + 1];
                float y0 = Bs[kk][tx * 2], y1 = Bs[kk][tx * 2 + 1];
                float d00 = x0 - y0, d01 = x0 - y1, d10 = x1 - y0, d11 = x1 - y1;
                a00 += d00 * d00; a01 += d01 * d01; a10 += d10 * d10; a11 += d11 * d11;
            }
            __syncthreads();
        }
        const int r0 = bi * 32 + ty * 2, c0 = bj * 32 + tx * 2;
        float s00 = sqrtf(a00), s01 = sqrtf(a01), s10 = sqrtf(a10), s11 = sqrtf(a11);
        dist[r0 * B + c0]           = s00;
        dist[r0 * B + c0 + 1]       = s01;
        dist[(r0 + 1) * B + c0]     = s10;
        dist[(r0 + 1) * B + c0 + 1] = s11;
        const int lr0 = labs[r0], lr1 = labs[r0 + 1];
        const int lc0 = labs[c0], lc1 = labs[c0 + 1];
        int cnt = 0;
        cnt += (lr0 != lc0) && (s00 <= MARGIN);
        cnt += (lr0 != lc1) && (s01 <= MARGIN);
        cnt += (lr1 != lc0) && (s10 <= MARGIN);
        cnt += (lr1 != lc1) && (s11 <= MARGIN);
        redI[t] = cnt; __syncthreads();
        for (int s = 128; s; s >>= 1) { if (t < s) redI[t] += redI[t + s]; __syncthreads(); }
        if (t == 0 && redI[0] > 0) atomicAdd(maskCnt, redI[0]);
    } else if (b < 768) {
        __shared__ float red[TPB];
        __shared__ int labs2[B];
        __shared__ int wsh;
        labs2[t] = labels[t]; labs2[t + 256] = labels[t + 256];
        if (t == 0) wsh = 1;
        __syncthreads();
        const int i = b - 256;
        const int li = labs2[i];
        const float2* crow = (const float2*)(centers + (size_t)li * D);
        const float2* frow = (const float2*)(features + (size_t)i * D);
        float2 c = crow[t], f = frow[t];
        ((float2*)(cgbuf + (size_t)i * D))[t] = c;
        float dx = c.x - f.x, dy = c.y - f.y;
        red[t] = fminf(fmaxf(dx * dx, 1e-12f), 1e12f) + fminf(fmaxf(dy * dy, 1e-12f), 1e12f);
        for (int j = i + 1 + t; j < B; j += TPB)
            if (labs2[j] == li) wsh = 0;          // benign race, same value
        __syncthreads();
        for (int s = 128; s; s >>= 1) { if (t < s) red[t] += red[t + s]; __syncthreads(); }
        if (t == 0) { rowLoss[i] = red[0]; winner[i] = wsh; }
    } else {
        copy_groups((const f4*)centers, (f4*)outAll, 1, CSPLIT, (b - 768) * TPB + t, 1280 * TPB);
    }
}

// ---- K2: 0-255 softmax-stats + W-on-the-fly GEMM -> vals; 256 loss+patch; 257+ copy ----
__global__ __launch_bounds__(TPB) void k2_gemm(
    const float* __restrict__ features, const int* __restrict__ labels,
    const float* __restrict__ centers, const float* __restrict__ cgbuf,
    const float* __restrict__ dist, const int* __restrict__ maskCnt,
    const float* __restrict__ rowLoss, float* __restrict__ vals,
    float* __restrict__ out, float* __restrict__ outAll)
{
    const int b = blockIdx.x, t = threadIdx.x;
    float* outC = out + 1;
    if (b < 256) {
        __shared__ float As[16][33];
        __shared__ float Bs[16][33];
        __shared__ int labs[B];
        __shared__ float mxs[32], invZs[32], rowSsh[32];
        labs[t] = labels[t]; labs[t + 256] = labels[t + 256];
        __syncthreads();
        const int bi = b >> 4, bj = b & 15;
        // per-row softmax stats: 8 lanes per row (rows bi*32 .. bi*32+31)
        {
            const int rg = t >> 3, lg = t & 7;
            const int row = bi * 32 + rg;
            const int lr = labs[row];
            const float* drow = dist + row * B;
            float mx = 0.f;
            for (int k = 0; k < 64; ++k) {
                int j = lg + 8 * k;
                float d = drow[j];
                bool m = (labs[j] != lr) && (d <= MARGIN);
                mx = fmaxf(mx, m ? d : 0.f);
            }
            #pragma unroll
            for (int o = 1; o < 8; o <<= 1) mx = fmaxf(mx, __shfl_xor(mx, o, 64));
            float sum = 0.f;
            for (int k = 0; k < 64; ++k) {
                int j = lg + 8 * k;
                float d = drow[j];
                bool m = (labs[j] != lr) && (d <= MARGIN);
                sum += m ? expf(mx - d) : 0.f;
            }
            #pragma unroll
            for (int o = 1; o < 8; o <<= 1) sum += __shfl_xor(sum, o, 64);
            if (lg == 0) {
                float Z = sum + 1e-6f;
                mxs[rg] = mx; invZs[rg] = 1.f / Z; rowSsh[rg] = sum / Z;
            }
        }
        __syncthreads();
        const float flagv = (*maskCnt > 0) ? 1.f : 0.f;
        const int tx = t & 15, ty = t >> 4;
        float a00 = 0.f, a01 = 0.f, a10 = 0.f, a11 = 0.f;
        for (int j0 = 0; j0 < B; j0 += 16) {
            #pragma unroll
            for (int it = 0; it < 2; ++it) {
                int idx = t + it * 256;
                int r = idx >> 4, jj = idx & 15;
                int j = j0 + jj;
                float d = dist[(size_t)(bi * 32 + r) * B + j];
                bool m = (labs[j] != labs[bi * 32 + r]) && (d <= MARGIN);
                As[jj][r] = m ? expf(mxs[r] - d) * invZs[r] : 0.f;
                int c = idx & 31, jj2 = idx >> 5;
                Bs[jj2][c] = cgbuf[(size_t)(j0 + jj2) * D + bj * 32 + c];
            }
            __syncthreads();
            #pragma unroll
            for (int kk = 0; kk < 16; ++kk) {
                float w0 = As[kk][ty * 2], w1 = As[kk][ty * 2 + 1];
                float c0 = Bs[kk][tx * 2], c1 = Bs[kk][tx * 2 + 1];
                a00 += w0 * c0; a01 += w0 * c1; a10 += w1 * c0; a11 += w1 * c1;
            }
            __syncthreads();
        }
        const int i0 = bi * 32 + ty * 2, i1 = i0 + 1;
        const int dcol = bj * 32 + tx * 2;
        const float s0 = rowSsh[ty * 2], s1 = rowSsh[ty * 2 + 1];
        float c, f;
        c = cgbuf[(size_t)i0 * D + dcol];     f = features[(size_t)i0 * D + dcol];
        vals[(size_t)i0 * D + dcol]     = 0.5f * (c + f) - BETA * flagv * (s0 * c - a00);
        c = cgbuf[(size_t)i0 * D + dcol + 1]; f = features[(size_t)i0 * D + dcol + 1];
        vals[(size_t)i0 * D + dcol + 1] = 0.5f * (c + f) - BETA * flagv * (s0 * c - a01);
        c = cgbuf[(size_t)i1 * D + dcol];     f = features[(size_t)i1 * D + dcol];
        vals[(size_t)i1 * D + dcol]     = 0.5f * (c + f) - BETA * flagv * (s1 * c - a10);
        c = cgbuf[(size_t)i1 * D + dcol + 1]; f = features[(size_t)i1 * D + dcol + 1];
        vals[(size_t)i1 * D + dcol + 1] = 0.5f * (c + f) - BETA * flagv * (s1 * c - a11);
    } else if (b == 256) {
        __shared__ float red[TPB];
        red[t] = rowLoss[t] + rowLoss[t + 256]; __syncthreads();
        for (int s = 128; s; s >>= 1) { if (t < s) red[t] += red[t + s]; __syncthreads(); }
        if (t == 0) out[0] = red[0] * (1.0f / ((float)B * (float)D));
        // head (centers[0..2]) and tail (centers[NFLOAT-1]) not covered by the group grid.
        // K3's scatter (next kernel) overwrites these if they belong to winner rows.
        if (t == 1) { outC[0] = centers[0]; outC[1] = centers[1]; outC[2] = centers[2]; }
        if (t == 2) { outC[NFLOAT - 1] = centers[NFLOAT - 1]; }
    } else {
        copy_groups((const f4*)centers, (f4*)outAll, CSPLIT, NG, (b - 257) * TPB + t, 1791 * TPB);
    }
}

// ---- K3: scatter winner rows from vals (runs after ALL copying complete) ----
__global__ __launch_bounds__(TPB) void k3_scatter(
    const float* __restrict__ vals, const int* __restrict__ labels,
    const int* __restrict__ winner, float* __restrict__ outC)
{
    const int b = blockIdx.x, t = threadIdx.x;
    const int i = b * 2 + (t >> 7);          // row 0..511
    const int dcol = (t & 127) * 4;
    if (!winner[i]) return;
    f4 v;
    __builtin_memcpy(&v, &vals[(size_t)i * D + dcol], 16);
    float* dst = outC + (size_t)labels[i] * D + dcol;   // 4B-aligned only
    __builtin_memcpy(dst, &v, 16);
}

extern "C" void kernel_launch(void* const* d_in, const int* in_sizes, int n_in,
                              void* d_out, int out_size, void* d_ws, size_t ws_size,
                              hipStream_t stream)
{
    const float* features = (const float*)d_in[0];
    const int*   labels   = (const int*)d_in[1];
    const float* centers  = (const float*)d_in[2];

    float* out  = (float*)d_out;     // out[0] = loss, out[1..] = new_centers
    float* outC = out + 1;

    char* ws = (char*)d_ws;
    float* cgbuf   = (float*)(ws);                 // 1 MB
    float* dist    = (float*)(ws + 1048576);       // 1 MB
    float* vals    = (float*)(ws + 2097152);       // 1 MB
    float* rowLoss = (float*)(ws + 3145728);       // 2 KB
    int*   winner  = (int*)  (ws + 3147776);       // 2 KB
    int*   maskCnt = (int*)  (ws + 3149824);       // 4 B

    hipMemsetAsync(maskCnt, 0, sizeof(int), stream);
    k1_dist<<<2048, TPB, 0, stream>>>(centers, features, labels, cgbuf, dist,
                                      rowLoss, winner, maskCnt, out);
    k2_gemm<<<2048, TPB, 0, stream>>>(features, labels, centers, cgbuf, dist, maskCnt,
                                      rowLoss, vals, out, out);
    k3_scatter<<<256, TPB, 0, stream>>>(vals, labels, winner, outC);
}